// Round 5
// baseline (3327.634 us; speedup 1.0000x reference)
//
#include <hip/hip_runtime.h>
#include <stdint.h>

typedef __attribute__((ext_vector_type(8))) __bf16 bf16x8;
typedef __attribute__((ext_vector_type(8))) short short8;
typedef __attribute__((ext_vector_type(4))) float f32x4;

#define LOG_P01 (-2.302585093f)   // log(0.1)

__device__ __forceinline__ uint16_t f2bf(float f) {
  union { float f; uint32_t u; } v; v.f = f;
  uint32_t r = (v.u + 0x7fffu + ((v.u >> 16) & 1u)) >> 16;
  return (uint16_t)r;
}
__device__ __forceinline__ float bf2f(uint16_t u) {
  union { uint32_t u; float f; } v; v.u = ((uint32_t)u) << 16;
  return v.f;
}
__device__ __forceinline__ float softplus1(float x) { return 1e-6f + log1pf(expf(x)); }

__device__ __forceinline__ void gload16(const void* g, void* l) {
  __builtin_amdgcn_global_load_lds(
      (__attribute__((address_space(1))) void*)(g),
      (__attribute__((address_space(3))) void*)(l), 16, 0, 0);
}

// ---------------------------------------------------------------------------
// prep_w: per 64x64 tile of W: sigma = 1e-6+softplus(W_p);
//   - write transposed, XOR-swizzled bf16 W_mu and sigma^2 (GEMM B operands)
//   - write plain-layout bf16 sigma (for sim_max)
//   - atomicAdd row/col norm^2 partials, KLD partial
// ---------------------------------------------------------------------------
__global__ __launch_bounds__(256) void prep_w_kernel(
    const float* __restrict__ Wmu0, const float* __restrict__ Wp0,
    const float* __restrict__ Wmu1, const float* __restrict__ Wp1,
    const float* __restrict__ Wmu2, const float* __restrict__ Wp2,
    uint16_t* __restrict__ Wt, uint16_t* __restrict__ St2,
    uint16_t* __restrict__ Sg,
    float* __restrict__ row2, float* __restrict__ col2, float* __restrict__ kld) {
  const int layer = blockIdx.z;
  const int ni = (layer == 0) ? 1024 : 2048;
  const int no = (layer == 2) ? 1024 : 2048;
  if ((int)blockIdx.x >= (ni >> 6) || (int)blockIdx.y >= (no >> 6)) return;
  const float* Wmu = layer == 0 ? Wmu0 : (layer == 1 ? Wmu1 : Wmu2);
  const float* Wp  = layer == 0 ? Wp0  : (layer == 1 ? Wp1  : Wp2);
  const size_t wofs = layer == 0 ? 0 : (layer == 1 ? 2097152 : 6291456);
  uint16_t* wt = Wt + wofs;
  uint16_t* st = St2 + wofs;
  uint16_t* sgb = Sg + wofs;
  float* r2 = row2 + layer * 2048;
  float* c2 = col2 + layer * 2048;

  __shared__ uint16_t lmu[64][72];
  __shared__ uint16_t ls2[64][72];
  __shared__ float red[256];

  const int t = threadIdx.x;
  const int i0 = blockIdx.x * 64, j0 = blockIdx.y * 64;
  const int w = t >> 6, lane = t & 63;
  float colpart = 0.f, kpart = 0.f;
#pragma unroll
  for (int rep = 0; rep < 16; ++rep) {
    int il = rep * 4 + w;
    int jl = lane;
    size_t gi = (size_t)(i0 + il) * no + (j0 + jl);
    float mu = Wmu[gi], p = Wp[gi];
    float sg = softplus1(p);
    float s2 = sg * sg;
    kpart += 2.f * (LOG_P01 - logf(sg)) - 1.f + 100.f * s2 + 100.f * mu * mu;
    float rs = s2;
    for (int o = 32; o; o >>= 1) rs += __shfl_xor(rs, o, 64);
    if (lane == 0) atomicAdd(&r2[i0 + il], rs);
    colpart += s2;
    sgb[gi] = f2bf(sg);
    lmu[jl][il] = f2bf(mu);
    ls2[jl][il] = f2bf(s2);
  }
  red[t] = colpart;
  __syncthreads();
  if (t < 64) {
    float cs = red[t] + red[64 + t] + red[128 + t] + red[192 + t];
    atomicAdd(&c2[j0 + t], cs);
  }
  // transposed, swizzled write-out (16B chunks): row j, byte (k*2)^((j&7)<<4)
  const int Kb = ni * 2;
#pragma unroll
  for (int cc = 0; cc < 2; ++cc) {
    int c = cc * 256 + t;
    int nl = c >> 3, kc = c & 7;
    short8 vmu = *(const short8*)((const char*)&lmu[0][0] + nl * 144 + kc * 16);
    short8 vs2 = *(const short8*)((const char*)&ls2[0][0] + nl * 144 + kc * 16);
    size_t db = (size_t)(j0 + nl) * Kb + (((i0 * 2 + kc * 16)) ^ ((nl & 7) << 4));
    *(short8*)((char*)wt + db) = vmu;
    *(short8*)((char*)st + db) = vs2;
  }
  __syncthreads();
  red[t] = kpart;
  __syncthreads();
  for (int o = 128; o >= 1; o >>= 1) {
    if (t < o) red[t] += red[t + o];
    __syncthreads();
  }
  if (t == 0) atomicAdd(kld, 0.5f * red[0]);
}

// ---------------------------------------------------------------------------
// prep_x: bf16(x), bf16(x*x) into swizzled [8192][1024] layout
// ---------------------------------------------------------------------------
__global__ __launch_bounds__(256) void prep_x_kernel(const float* __restrict__ x,
                                                     uint16_t* __restrict__ Ah,
                                                     uint16_t* __restrict__ Ah2) {
  size_t c = (size_t)blockIdx.x * 256 + threadIdx.x;  // 8-elem chunk
  size_t gidx = c * 8;
  if (gidx >= (size_t)8192 * 1024) return;
  int m = (int)(gidx >> 10);
  int k0 = (int)(gidx & 1023);
  const float4* xp = (const float4*)(x + gidx);
  float4 a = xp[0], b = xp[1];
  float vals[8] = {a.x, a.y, a.z, a.w, b.x, b.y, b.z, b.w};
  union { uint16_t u[8]; short8 v; } ph, ph2;
#pragma unroll
  for (int e = 0; e < 8; ++e) {
    float f = vals[e];
    ph.u[e] = f2bf(f);
    ph2.u[e] = f2bf(f * f);
  }
  size_t ob = (size_t)m * 2048 + ((k0 * 2) ^ ((m & 7) << 4));
  *(short8*)((char*)Ah + ob) = ph.v;
  *(short8*)((char*)Ah2 + ob) = ph2.v;
}

// ---------------------------------------------------------------------------
// prep_bias: bias[n] = b_mu + softplus(b_p)*eps_b ; bias KLD
// ---------------------------------------------------------------------------
__global__ __launch_bounds__(256) void prep_bias_kernel(
    const float* bmu0, const float* bp0, const float* eb0,
    const float* bmu1, const float* bp1, const float* eb1,
    const float* bmu2, const float* bp2, const float* eb2,
    float* __restrict__ bias, float* __restrict__ kld) {
  int t = blockIdx.x * 256 + threadIdx.x;
  float kpart = 0.f;
  if (t < 5120) {
    int layer = t < 2048 ? 0 : (t < 4096 ? 1 : 2);
    int n = t - (layer == 0 ? 0 : (layer == 1 ? 2048 : 4096));
    const float* bmu = layer == 0 ? bmu0 : (layer == 1 ? bmu1 : bmu2);
    const float* bp  = layer == 0 ? bp0  : (layer == 1 ? bp1  : bp2);
    const float* eb  = layer == 0 ? eb0  : (layer == 1 ? eb1  : eb2);
    float mu = bmu[n], p = bp[n], e = eb[n];
    float sg = softplus1(p);
    bias[layer * 2048 + n] = mu + sg * e;
    kpart = 0.5f * (2.f * (LOG_P01 - logf(sg)) - 1.f + 100.f * sg * sg + 100.f * mu * mu);
  }
  for (int o = 32; o; o >>= 1) kpart += __shfl_xor(kpart, o, 64);
  if ((threadIdx.x & 63) == 0) atomicAdd(kld, kpart);
}

// ---------------------------------------------------------------------------
// sim_max: single linear grid-stride pass over concatenated sim (320MB).
// ---------------------------------------------------------------------------
__global__ __launch_bounds__(256) void sim_max_kernel(
    const float* __restrict__ s0, const float* __restrict__ s1,
    const float* __restrict__ s2, const uint16_t* __restrict__ Sg,
    float* __restrict__ partial) {
  __shared__ int lmax[30];
  if (threadIdx.x < 30) lmax[threadIdx.x] = 0;
  __syncthreads();
  const size_t stride = (size_t)gridDim.x * 256;
  for (size_t c = (size_t)blockIdx.x * 256 + threadIdx.x; c < 20971520; c += stride) {
    const float* sp; size_t within; const uint16_t* sgp; int slot_base, shift;
    if (c < 5242880)       { sp = s0; within = c;            sgp = Sg;           slot_base = 0;  shift = 19; }
    else if (c < 15728640) { sp = s1; within = c - 5242880;  sgp = Sg + 2097152; slot_base = 10; shift = 20; }
    else                   { sp = s2; within = c - 15728640; sgp = Sg + 6291456; slot_base = 20; shift = 19; }
    int s = (int)(within >> shift);
    size_t idx = within - ((size_t)s << shift);
    float4 v = ((const float4*)sp)[within];
    ushort4 sv = *(const ushort4*)(sgp + idx * 4);
    float m = fmaxf(fmaxf(v.x * bf2f(sv.x), v.y * bf2f(sv.y)),
                    fmaxf(v.z * bf2f(sv.z), v.w * bf2f(sv.w)));
    for (int o = 32; o; o >>= 1) m = fmaxf(m, __shfl_xor(m, o, 64));
    if ((threadIdx.x & 63) == 0)
      atomicMax(&lmax[slot_base + s], __float_as_int(fmaxf(m, 0.f)));
  }
  __syncthreads();
  if (threadIdx.x < 30)
    partial[threadIdx.x * 2048 + blockIdx.x] = __int_as_float(lmax[threadIdx.x]);
}

// ---------------------------------------------------------------------------
// gemm_nt (3 layers in one launch): C = R @ R^T, R = Wt rows (bf16 swizzled).
// ---------------------------------------------------------------------------
__global__ __launch_bounds__(256, 2) void gemm_nt_kernel(
    const uint16_t* __restrict__ Wt, float* __restrict__ Bmat) {
  const int layer = blockIdx.z;
  const int K = (layer == 0) ? 1024 : 2048;
  const int N = (layer == 2) ? 1024 : 2048;
  if ((int)blockIdx.x >= (N >> 7) || (int)blockIdx.y >= (N >> 7)) return;
  const uint16_t* R = Wt + (layer == 0 ? 0 : (layer == 1 ? 2097152 : 6291456));
  float* C = Bmat + (layer == 0 ? 0 : (layer == 1 ? 4194304 : 8388608));

  __shared__ uint16_t lds[16384];  // 32KB: A-tile [128][64] | B-tile [128][64]
  const int t = threadIdx.x;
  const int w = t >> 6, lane = t & 63;
  const int m0 = blockIdx.y * 128, n0 = blockIdx.x * 128;
  const int wm = (w >> 1) * 64, wn = (w & 1) * 64;
  const size_t Kb = (size_t)K * 2;

  f32x4 zero = {0.f, 0.f, 0.f, 0.f};
  f32x4 acc[4][4];
#pragma unroll
  for (int i = 0; i < 4; ++i)
#pragma unroll
    for (int j = 0; j < 4; ++j) acc[i][j] = zero;

  const int rb = ((w < 2) ? m0 : n0) + (w & 1) * 64;
  const char* gsrc = (const char*)R + (size_t)rb * Kb;
  uint16_t* ltile = lds + (w < 2 ? 0 : 8192) + (w & 1) * 4096;
  const int lrow = lane >> 3;
  const int lcol = (lane & 7) * 16;

  int offA[4][2], offB[4][2];
#pragma unroll
  for (int i = 0; i < 4; ++i) {
    int rowa = wm + i * 16 + (lane & 15);
    int rowb = wn + i * 16 + (lane & 15);
    int kp = (lane >> 4) << 4;
#pragma unroll
    for (int kk = 0; kk < 2; ++kk) {
      offA[i][kk] = (rowa << 7) + (((kk << 6) + kp) ^ ((rowa & 7) << 4));
      offB[i][kk] = (rowb << 7) + (((kk << 6) + kp) ^ ((rowb & 7) << 4));
    }
  }
  const char* ldsc = (const char*)lds;
  const int nkt = K >> 6;
  for (int kt = 0; kt < nkt; ++kt) {
    const char* gb = gsrc + (size_t)kt * 128;
#pragma unroll
    for (int r = 0; r < 8; ++r) {
      gload16(gb + (size_t)(r * 8 + lrow) * Kb + lcol, ltile + r * 512);
    }
    __syncthreads();
#pragma unroll
    for (int kk = 0; kk < 2; ++kk) {
      bf16x8 af[4], bfr[4];
#pragma unroll
      for (int i = 0; i < 4; ++i) {
        af[i]  = *(const bf16x8*)(ldsc + offA[i][kk]);
        bfr[i] = *(const bf16x8*)(ldsc + 16384 + offB[i][kk]);
      }
#pragma unroll
      for (int i = 0; i < 4; ++i)
#pragma unroll
        for (int j = 0; j < 4; ++j)
          acc[i][j] = __builtin_amdgcn_mfma_f32_16x16x32_bf16(af[i], bfr[j], acc[i][j], 0, 0, 0);
    }
    __syncthreads();
  }
#pragma unroll
  for (int j = 0; j < 4; ++j) {
    int n = n0 + wn + j * 16 + (lane & 15);
#pragma unroll
    for (int i = 0; i < 4; ++i) {
      int mb = m0 + wm + i * 16 + ((lane >> 4) << 2);
      f32x4 a = acc[i][j];
#pragma unroll
      for (int r = 0; r < 4; ++r) C[(size_t)(mb + r) * N + n] = a[r];
    }
  }
}

// ---------------------------------------------------------------------------
// v1: v = W^T u0 per layer — wave per row of Wt (bf16 swizzled), fp32 accum
// ---------------------------------------------------------------------------
__global__ __launch_bounds__(256) void v1_kernel(const uint16_t* __restrict__ Wt,
                                                 const float* u00, const float* u01,
                                                 const float* u02,
                                                 float* __restrict__ vout) {
  int gw = (blockIdx.x * 256 + threadIdx.x) >> 6;  // 0..5119
  int lane = threadIdx.x & 63;
  int layer = gw < 2048 ? 0 : (gw < 4096 ? 1 : 2);
  int j = gw - (layer == 0 ? 0 : (layer == 1 ? 2048 : 4096));
  int ni = layer == 0 ? 1024 : 2048;
  const uint16_t* row = Wt + (layer == 0 ? 0 : (layer == 1 ? 2097152 : 6291456)) + (size_t)j * ni;
  const float* u0 = layer == 0 ? u00 : (layer == 1 ? u01 : u02);
  int nc = ni >> 3;
  float part = 0.f;
  for (int c = lane; c < nc; c += 64) {
    int bo = (c * 16) ^ ((j & 7) << 4);
    short8 v = *(const short8*)((const char*)row + bo);
    const float4* up = (const float4*)(u0 + c * 8);
    float4 a = up[0], b = up[1];
    float us[8] = {a.x, a.y, a.z, a.w, b.x, b.y, b.z, b.w};
#pragma unroll
    for (int e = 0; e < 8; ++e) part += bf2f((uint16_t)((short*)&v)[e]) * us[e];
  }
  for (int o = 32; o; o >>= 1) part += __shfl_xor(part, o, 64);
  if (lane == 0) vout[layer * 2048 + j] = part;
}

// ---------------------------------------------------------------------------
// bmv: vout = B vin for all 3 layers (wave per row, fp32)
// ---------------------------------------------------------------------------
__global__ __launch_bounds__(256) void bmv_kernel(const float* __restrict__ Bm,
                                                  const float* __restrict__ vin,
                                                  float* __restrict__ vout) {
  int gw = (blockIdx.x * 256 + threadIdx.x) >> 6;  // 0..5119
  int lane = threadIdx.x & 63;
  int layer = gw < 2048 ? 0 : (gw < 4096 ? 1 : 2);
  int r = gw - (layer == 0 ? 0 : (layer == 1 ? 2048 : 4096));
  int n = layer == 2 ? 1024 : 2048;
  const float* row = Bm + (layer == 0 ? 0 : (layer == 1 ? 4194304 : 8388608)) + (size_t)r * n;
  const float* v = vin + layer * 2048;
  float part = 0.f;
  for (int c = lane * 4; c < n; c += 256) {
    float4 w4 = *(const float4*)(row + c);
    float4 v4 = *(const float4*)(v + c);
    part += w4.x * v4.x + w4.y * v4.y + w4.z * v4.z + w4.w * v4.w;
  }
  for (int o = 32; o; o >>= 1) part += __shfl_xor(part, o, 64);
  if (lane == 0) vout[layer * 2048 + r] = part;
}

// ---------------------------------------------------------------------------
// dual GEMM: BK=32, single 32KB buffer, stage-under-MFMA (T3-minimum).
// LDS: 4 mats x [128][32] bf16 = 32KB -> 3-4 blocks/CU.
// Bank swizzle: logical granule g stored at physical p = g ^ h(row),
// h(row) = (row>>1)&3  (bijective in bank space: slot = (row&1)*4 + p).
// Global arrays carry byte-XOR (row&7)<<4; staging source compensates it
// EXACTLY so the logical k recovered is row-independent (true MFMA pairing):
//   srcbyte = (kt*64 + ((lane&3)^((lane>>3)&3))<<4) ^ (((lane>>2)&7)<<4)
// ---------------------------------------------------------------------------
__global__ __launch_bounds__(256, 3) void gemm_dual_kernel(
    const uint16_t* __restrict__ Ab, const uint16_t* __restrict__ A2b,
    const uint16_t* __restrict__ Bb, const uint16_t* __restrict__ B2b,
    const float* __restrict__ eps, const float* __restrict__ bias,
    uint16_t* __restrict__ Oh, uint16_t* __restrict__ Oh2,
    float* __restrict__ Oy, int K, int N, int last, int nwgx) {
  __shared__ uint16_t lds[16384];  // 32KB: A | A2 | B | B2, each [128][32]
  const int t = threadIdx.x;
  const int w = t >> 6, lane = t & 63;

  // T1: bijective XCD swizzle (grid always % 8 == 0 here)
  const int nwg = gridDim.x;
  const int cpx = nwg >> 3;
  const int bid = blockIdx.x;
  const int logical = (bid & 7) * cpx + (bid >> 3);
  const int bx = logical % nwgx, by = logical / nwgx;

  const int m0 = by * 128, n0 = bx * 128;
  const int wm = (w >> 1) * 64, wn = (w & 1) * 64;
  const size_t Kb = (size_t)K * 2;

  f32x4 zero = {0.f, 0.f, 0.f, 0.f};
  f32x4 accm[4][4], accs[4][4];
#pragma unroll
  for (int i = 0; i < 4; ++i)
#pragma unroll
    for (int j = 0; j < 4; ++j) { accm[i][j] = zero; accs[i][j] = zero; }

  // staging: wave w stages matrix w (A, A2, B, B2), 8KB per K-tile
  const uint16_t* mats[4] = {Ab, A2b, Bb, B2b};
  const int rbase = (w < 2) ? m0 : n0;
  const char* gsrc = (const char*)mats[w] + (size_t)rbase * Kb;
  const int rowq = lane >> 2;  // row within 16-row chunk
  // source byte (excl. kt term): swizzle + exact global-XOR compensation
  const int soff = ((((lane & 3) ^ ((lane >> 3) & 3)) << 4));
  const int gmask = (((lane >> 2) & 7) << 4);
  char* lw = (char*)lds + w * 8192;

  // ds_read: physical granule = q ^ h(row'), h(row') = (lane>>1)&3
  const int kx = (((lane >> 4) ^ ((lane >> 1) & 3)) << 4);
  int offA[4], offB[4];
#pragma unroll
  for (int i = 0; i < 4; ++i) {
    offA[i] = ((wm + i * 16 + (lane & 15)) << 6) + kx;
    offB[i] = ((wn + i * 16 + (lane & 15)) << 6) + kx;
  }

  const int nkt = K >> 5;
  // prologue: stage K-tile 0
  {
    int srcb = (0 * 64 + soff) ^ gmask;
#pragma unroll
    for (int rr = 0; rr < 8; ++rr)
      gload16(gsrc + (size_t)(rr * 16 + rowq) * Kb + srcb, lw + rr * 1024 + lane * 16);
  }

  const char* sb = (const char*)lds;
  for (int kt = 0; kt < nkt; ++kt) {
    __syncthreads();  // stage[kt] complete (drains vmcnt)
    bf16x8 af[4], a2f[4], bfr[4], b2f[4];
#pragma unroll
    for (int i = 0; i < 4; ++i) {
      af[i]  = *(const bf16x8*)(sb + offA[i]);
      a2f[i] = *(const bf16x8*)(sb + 8192 + offA[i]);
      bfr[i] = *(const bf16x8*)(sb + 16384 + offB[i]);
      b2f[i] = *(const bf16x8*)(sb + 24576 + offB[i]);
    }
    __syncthreads();  // all waves' reads done -> LDS reusable
    if (kt + 1 < nkt) {
      int srcb = ((kt + 1) * 64 + soff) ^ gmask;
#pragma unroll
      for (int rr = 0; rr < 8; ++rr)
        gload16(gsrc + (size_t)(rr * 16 + rowq) * Kb + srcb, lw + rr * 1024 + lane * 16);
    }
#pragma unroll
    for (int i = 0; i < 4; ++i)
#pragma unroll
      for (int j = 0; j < 4; ++j) {
        accm[i][j] = __builtin_amdgcn_mfma_f32_16x16x32_bf16(af[i], bfr[j], accm[i][j], 0, 0, 0);
        accs[i][j] = __builtin_amdgcn_mfma_f32_16x16x32_bf16(a2f[i], b2f[j], accs[i][j], 0, 0, 0);
      }
  }

  // epilogue
  const int nstrb = N * 2;
#pragma unroll
  for (int j = 0; j < 4; ++j) {
    int n = n0 + wn + j * 16 + (lane & 15);
    float bn = bias[n];
#pragma unroll
    for (int i = 0; i < 4; ++i) {
      int mb = m0 + wm + i * 16 + ((lane >> 4) << 2);
      f32x4 am = accm[i][j], as = accs[i][j];
#pragma unroll
      for (int r = 0; r < 4; ++r) {
        int m = mb + r;
        float sd = sqrtf(fmaxf(as[r], 0.f));
        float val = am[r] + sd * eps[(size_t)m * N + n] + bn;
        if (last) {
          Oy[(size_t)m * N + n] = val;
        } else {
          float h = fmaxf(val, 0.f);
          size_t ob = (size_t)m * nstrb + ((n * 2) ^ ((m & 7) << 4));
          *(uint16_t*)((char*)Oh + ob) = f2bf(h);
          *(uint16_t*)((char*)Oh2 + ob) = f2bf(h * h);
        }
      }
    }
  }
}

// ---------------------------------------------------------------------------
// finalize: reduce sim partials; tkld, tlip.
// sigma = sqrt(dot(v10,Bv10)/dot(v10,v10))
// ---------------------------------------------------------------------------
__device__ __forceinline__ float block_red(float v, int is_max, float* red) {
  int t = threadIdx.x;
  red[t] = v;
  __syncthreads();
  for (int o = 128; o >= 1; o >>= 1) {
    if (t < o) red[t] = is_max ? fmaxf(red[t], red[t + o]) : (red[t] + red[t + o]);
    __syncthreads();
  }
  float r = red[0];
  __syncthreads();
  return r;
}

__global__ __launch_bounds__(256) void finalize_kernel(const float* __restrict__ acc,
                                                       const float* __restrict__ v10,
                                                       const float* __restrict__ wv,
                                                       const float* __restrict__ partial,
                                                       float* __restrict__ out2) {
  __shared__ float red[256];
  __shared__ float smax[30];
  int t = threadIdx.x;
  int w = t >> 6, lane = t & 63;
  for (int sl = w; sl < 30; sl += 4) {
    float m = 0.f;
    for (int b = lane; b < 2048; b += 64) m = fmaxf(m, partial[sl * 2048 + b]);
    for (int o = 32; o; o >>= 1) m = fmaxf(m, __shfl_xor(m, o, 64));
    if (lane == 0) smax[sl] = m;
  }
  __syncthreads();
  float tlip = 0.f;
  for (int layer = 0; layer < 3; ++layer) {
    int ni = layer == 0 ? 1024 : 2048;
    int no = layer == 2 ? 1024 : 2048;
    float mr = 0.f, mc = 0.f, s2n = 0.f, s2d = 0.f;
    for (int i = t; i < ni; i += 256) mr = fmaxf(mr, acc[64 + layer * 2048 + i]);
    for (int j = t; j < no; j += 256) mc = fmaxf(mc, acc[6208 + layer * 2048 + j]);
    for (int j = t; j < no; j += 256) {
      float v = v10[layer * 2048 + j], wv_ = wv[layer * 2048 + j];
      s2n += v * wv_;
      s2d += v * v;
    }
    mr = block_red(mr, 1, red);
    mc = block_red(mc, 1, red);
    s2n = block_red(s2n, 0, red);
    s2d = block_red(s2d, 0, red);
    if (t == 0) {
      float sm = 0.f;
      for (int s = 0; s < 10; ++s) sm += smax[layer * 10 + s];
      sm *= 0.1f;
      float sigma = sqrtf(s2n / s2d);
      float res = sqrtf(mr) + sqrtf(mc);
      float l = res + sm + sigma;
      tlip += l * l;
    }
  }
  if (t == 0) {
    out2[0] = acc[0];
    out2[1] = tlip;
  }
}

// ---------------------------------------------------------------------------
extern "C" void kernel_launch(void* const* d_in, const int* in_sizes, int n_in,
                              void* d_out, int out_size, void* d_ws, size_t ws_size,
                              hipStream_t stream) {
  (void)in_sizes; (void)n_in; (void)out_size; (void)ws_size;
  const float* x = (const float*)d_in[0];
  const float* Wmu[3] = {(const float*)d_in[1], (const float*)d_in[9],  (const float*)d_in[17]};
  const float* Wp[3]  = {(const float*)d_in[2], (const float*)d_in[10], (const float*)d_in[18]};
  const float* bmu[3] = {(const float*)d_in[3], (const float*)d_in[11], (const float*)d_in[19]};
  const float* bp[3]  = {(const float*)d_in[4], (const float*)d_in[12], (const float*)d_in[20]};
  const float* epsw[3]= {(const float*)d_in[5], (const float*)d_in[13], (const float*)d_in[21]};
  const float* epsb[3]= {(const float*)d_in[6], (const float*)d_in[14], (const float*)d_in[22]};
  const float* u0[3]  = {(const float*)d_in[7], (const float*)d_in[15], (const float*)d_in[23]};
  const float* sim[3] = {(const float*)d_in[8], (const float*)d_in[16], (const float*)d_in[24]};

  char* ws = (char*)d_ws;
  uint16_t* A0h  = (uint16_t*)(ws);
  uint16_t* A0h2 = (uint16_t*)(ws + 33554432);
  uint16_t* A1h  = (uint16_t*)(ws + 67108864);
  uint16_t* A1h2 = (uint16_t*)(ws + 100663296);
  float*    Bmat = (float*)(ws + 67108864);     // aliases A1h: dead before gemm1
  uint16_t* Sgbf = (uint16_t*)(ws + 104857600); // aliases A1h2 tail: dead before gemm1
  uint16_t* Wt   = (uint16_t*)(ws + 134217728);
  uint16_t* St2  = (uint16_t*)(ws + 150994944);
  float* bias    = (float*)(ws + 167772160);
  float* pbuf0   = (float*)(ws + 167796736);
  float* pbuf1   = (float*)(ws + 167821312);
  float* acc     = (float*)(ws + 167845888);
  float* partial = (float*)(ws + 167895296);    // 30*2048 floats
  // acc layout: [0] kld | [64..6207] row2 | [6208..12351] col2

  hipMemsetAsync(ws + 167845888, 0, 49408, stream);

  prep_w_kernel<<<dim3(32, 32, 3), 256, 0, stream>>>(
      Wmu[0], Wp[0], Wmu[1], Wp[1], Wmu[2], Wp[2], Wt, St2, Sgbf, acc + 64, acc + 6208, acc);
  prep_x_kernel<<<4096, 256, 0, stream>>>(x, A0h, A0h2);
  prep_bias_kernel<<<20, 256, 0, stream>>>(
      bmu[0], bp[0], epsb[0], bmu[1], bp[1], epsb[1], bmu[2], bp[2], epsb[2], bias, acc);
  sim_max_kernel<<<2048, 256, 0, stream>>>(sim[0], sim[1], sim[2], Sgbf, partial);

  // B = W^T W per layer (bf16 MFMA from Wt rows), one launch
  gemm_nt_kernel<<<dim3(16, 16, 3), 256, 0, stream>>>(Wt, Bmat);

  // v1 = W^T u0 ; then v_{k+1} = B v_k ; v10 in pbuf1, w = B v10 in pbuf0
  v1_kernel<<<1280, 256, 0, stream>>>(Wt, u0[0], u0[1], u0[2], pbuf0);
  for (int it = 0; it < 10; ++it) {
    const float* vin = (it & 1) ? pbuf1 : pbuf0;
    float* vout = (it & 1) ? pbuf0 : pbuf1;
    bmv_kernel<<<1280, 256, 0, stream>>>(Bmat, vin, vout);
  }

  float* y = (float*)d_out;
  gemm_dual_kernel<<<1024, 256, 0, stream>>>(
      A0h, A0h2, Wt, St2, epsw[0], bias, A1h, A1h2, nullptr, 1024, 2048, 0, 16);
  gemm_dual_kernel<<<1024, 256, 0, stream>>>(
      A1h, A1h2, Wt + 2097152, St2 + 2097152, epsw[1], bias + 2048, A0h, A0h2, nullptr, 2048, 2048, 0, 16);
  gemm_dual_kernel<<<512, 256, 0, stream>>>(
      A0h, A0h2, Wt + 6291456, St2 + 6291456, epsw[2], bias + 4096, nullptr, nullptr, y, 2048, 1024, 1, 8);

  finalize_kernel<<<1, 256, 0, stream>>>(acc, pbuf1, pbuf0, partial, y + 8388608);
}

// Round 6
// 916.493 us; speedup vs baseline: 3.6308x; 3.6308x over previous
//
#include <hip/hip_runtime.h>
#include <stdint.h>

typedef __attribute__((ext_vector_type(8))) __bf16 bf16x8;
typedef __attribute__((ext_vector_type(8))) short short8;
typedef __attribute__((ext_vector_type(4))) float f32x4;

#define LOG_P01 (-2.302585093f)   // log(0.1)

__device__ __forceinline__ uint16_t f2bf(float f) {
  union { float f; uint32_t u; } v; v.f = f;
  uint32_t r = (v.u + 0x7fffu + ((v.u >> 16) & 1u)) >> 16;
  return (uint16_t)r;
}
__device__ __forceinline__ float bf2f(uint16_t u) {
  union { uint32_t u; float f; } v; v.u = ((uint32_t)u) << 16;
  return v.f;
}
__device__ __forceinline__ float softplus1(float x) { return 1e-6f + log1pf(expf(x)); }

__device__ __forceinline__ void gload16(const void* g, void* l) {
  __builtin_amdgcn_global_load_lds(
      (__attribute__((address_space(1))) void*)(g),
      (__attribute__((address_space(3))) void*)(l), 16, 0, 0);
}

// ---------------------------------------------------------------------------
// prep_w: per 64x64 tile of W: sigma = 1e-6+softplus(W_p);
//   - write transposed, XOR-swizzled bf16 W_mu and sigma^2 (GEMM B operands)
//   - write plain-layout bf16 sigma (for sim_max)
//   - atomicAdd row/col norm^2 partials, KLD partial
// ---------------------------------------------------------------------------
__global__ __launch_bounds__(256) void prep_w_kernel(
    const float* __restrict__ Wmu0, const float* __restrict__ Wp0,
    const float* __restrict__ Wmu1, const float* __restrict__ Wp1,
    const float* __restrict__ Wmu2, const float* __restrict__ Wp2,
    uint16_t* __restrict__ Wt, uint16_t* __restrict__ St2,
    uint16_t* __restrict__ Sg,
    float* __restrict__ row2, float* __restrict__ col2, float* __restrict__ kld) {
  const int layer = blockIdx.z;
  const int ni = (layer == 0) ? 1024 : 2048;
  const int no = (layer == 2) ? 1024 : 2048;
  if ((int)blockIdx.x >= (ni >> 6) || (int)blockIdx.y >= (no >> 6)) return;
  const float* Wmu = layer == 0 ? Wmu0 : (layer == 1 ? Wmu1 : Wmu2);
  const float* Wp  = layer == 0 ? Wp0  : (layer == 1 ? Wp1  : Wp2);
  const size_t wofs = layer == 0 ? 0 : (layer == 1 ? 2097152 : 6291456);
  uint16_t* wt = Wt + wofs;
  uint16_t* st = St2 + wofs;
  uint16_t* sgb = Sg + wofs;
  float* r2 = row2 + layer * 2048;
  float* c2 = col2 + layer * 2048;

  __shared__ uint16_t lmu[64][72];
  __shared__ uint16_t ls2[64][72];
  __shared__ float red[256];

  const int t = threadIdx.x;
  const int i0 = blockIdx.x * 64, j0 = blockIdx.y * 64;
  const int w = t >> 6, lane = t & 63;
  float colpart = 0.f, kpart = 0.f;
#pragma unroll
  for (int rep = 0; rep < 16; ++rep) {
    int il = rep * 4 + w;
    int jl = lane;
    size_t gi = (size_t)(i0 + il) * no + (j0 + jl);
    float mu = Wmu[gi], p = Wp[gi];
    float sg = softplus1(p);
    float s2 = sg * sg;
    kpart += 2.f * (LOG_P01 - logf(sg)) - 1.f + 100.f * s2 + 100.f * mu * mu;
    float rs = s2;
    for (int o = 32; o; o >>= 1) rs += __shfl_xor(rs, o, 64);
    if (lane == 0) atomicAdd(&r2[i0 + il], rs);
    colpart += s2;
    sgb[gi] = f2bf(sg);
    lmu[jl][il] = f2bf(mu);
    ls2[jl][il] = f2bf(s2);
  }
  red[t] = colpart;
  __syncthreads();
  if (t < 64) {
    float cs = red[t] + red[64 + t] + red[128 + t] + red[192 + t];
    atomicAdd(&c2[j0 + t], cs);
  }
  // transposed, swizzled write-out (16B chunks): row j, byte (k*2)^((j&7)<<4)
  const int Kb = ni * 2;
#pragma unroll
  for (int cc = 0; cc < 2; ++cc) {
    int c = cc * 256 + t;
    int nl = c >> 3, kc = c & 7;
    short8 vmu = *(const short8*)((const char*)&lmu[0][0] + nl * 144 + kc * 16);
    short8 vs2 = *(const short8*)((const char*)&ls2[0][0] + nl * 144 + kc * 16);
    size_t db = (size_t)(j0 + nl) * Kb + (((i0 * 2 + kc * 16)) ^ ((nl & 7) << 4));
    *(short8*)((char*)wt + db) = vmu;
    *(short8*)((char*)st + db) = vs2;
  }
  __syncthreads();
  red[t] = kpart;
  __syncthreads();
  for (int o = 128; o >= 1; o >>= 1) {
    if (t < o) red[t] += red[t + o];
    __syncthreads();
  }
  if (t == 0) atomicAdd(kld, 0.5f * red[0]);
}

// ---------------------------------------------------------------------------
// prep_x: bf16(x), bf16(x*x) into swizzled [8192][1024] layout
// ---------------------------------------------------------------------------
__global__ __launch_bounds__(256) void prep_x_kernel(const float* __restrict__ x,
                                                     uint16_t* __restrict__ Ah,
                                                     uint16_t* __restrict__ Ah2) {
  size_t c = (size_t)blockIdx.x * 256 + threadIdx.x;  // 8-elem chunk
  size_t gidx = c * 8;
  if (gidx >= (size_t)8192 * 1024) return;
  int m = (int)(gidx >> 10);
  int k0 = (int)(gidx & 1023);
  const float4* xp = (const float4*)(x + gidx);
  float4 a = xp[0], b = xp[1];
  float vals[8] = {a.x, a.y, a.z, a.w, b.x, b.y, b.z, b.w};
  union { uint16_t u[8]; short8 v; } ph, ph2;
#pragma unroll
  for (int e = 0; e < 8; ++e) {
    float f = vals[e];
    ph.u[e] = f2bf(f);
    ph2.u[e] = f2bf(f * f);
  }
  size_t ob = (size_t)m * 2048 + ((k0 * 2) ^ ((m & 7) << 4));
  *(short8*)((char*)Ah + ob) = ph.v;
  *(short8*)((char*)Ah2 + ob) = ph2.v;
}

// ---------------------------------------------------------------------------
// prep_bias: bias[n] = b_mu + softplus(b_p)*eps_b ; bias KLD
// ---------------------------------------------------------------------------
__global__ __launch_bounds__(256) void prep_bias_kernel(
    const float* bmu0, const float* bp0, const float* eb0,
    const float* bmu1, const float* bp1, const float* eb1,
    const float* bmu2, const float* bp2, const float* eb2,
    float* __restrict__ bias, float* __restrict__ kld) {
  int t = blockIdx.x * 256 + threadIdx.x;
  float kpart = 0.f;
  if (t < 5120) {
    int layer = t < 2048 ? 0 : (t < 4096 ? 1 : 2);
    int n = t - (layer == 0 ? 0 : (layer == 1 ? 2048 : 4096));
    const float* bmu = layer == 0 ? bmu0 : (layer == 1 ? bmu1 : bmu2);
    const float* bp  = layer == 0 ? bp0  : (layer == 1 ? bp1  : bp2);
    const float* eb  = layer == 0 ? eb0  : (layer == 1 ? eb1  : eb2);
    float mu = bmu[n], p = bp[n], e = eb[n];
    float sg = softplus1(p);
    bias[layer * 2048 + n] = mu + sg * e;
    kpart = 0.5f * (2.f * (LOG_P01 - logf(sg)) - 1.f + 100.f * sg * sg + 100.f * mu * mu);
  }
  for (int o = 32; o; o >>= 1) kpart += __shfl_xor(kpart, o, 64);
  if ((threadIdx.x & 63) == 0) atomicAdd(kld, kpart);
}

// ---------------------------------------------------------------------------
// sim_max: single linear grid-stride pass over concatenated sim (320MB).
// ---------------------------------------------------------------------------
__global__ __launch_bounds__(256) void sim_max_kernel(
    const float* __restrict__ s0, const float* __restrict__ s1,
    const float* __restrict__ s2, const uint16_t* __restrict__ Sg,
    float* __restrict__ partial) {
  __shared__ int lmax[30];
  if (threadIdx.x < 30) lmax[threadIdx.x] = 0;
  __syncthreads();
  const size_t stride = (size_t)gridDim.x * 256;
  for (size_t c = (size_t)blockIdx.x * 256 + threadIdx.x; c < 20971520; c += stride) {
    const float* sp; size_t within; const uint16_t* sgp; int slot_base, shift;
    if (c < 5242880)       { sp = s0; within = c;            sgp = Sg;           slot_base = 0;  shift = 19; }
    else if (c < 15728640) { sp = s1; within = c - 5242880;  sgp = Sg + 2097152; slot_base = 10; shift = 20; }
    else                   { sp = s2; within = c - 15728640; sgp = Sg + 6291456; slot_base = 20; shift = 19; }
    int s = (int)(within >> shift);
    size_t idx = within - ((size_t)s << shift);
    float4 v = ((const float4*)sp)[within];
    ushort4 sv = *(const ushort4*)(sgp + idx * 4);
    float m = fmaxf(fmaxf(v.x * bf2f(sv.x), v.y * bf2f(sv.y)),
                    fmaxf(v.z * bf2f(sv.z), v.w * bf2f(sv.w)));
    for (int o = 32; o; o >>= 1) m = fmaxf(m, __shfl_xor(m, o, 64));
    if ((threadIdx.x & 63) == 0)
      atomicMax(&lmax[slot_base + s], __float_as_int(fmaxf(m, 0.f)));
  }
  __syncthreads();
  if (threadIdx.x < 30)
    partial[threadIdx.x * 2048 + blockIdx.x] = __int_as_float(lmax[threadIdx.x]);
}

// ---------------------------------------------------------------------------
// gemm_nt (3 layers in one launch): C = R @ R^T, R = Wt rows (bf16 swizzled).
// ---------------------------------------------------------------------------
__global__ __launch_bounds__(256, 2) void gemm_nt_kernel(
    const uint16_t* __restrict__ Wt, float* __restrict__ Bmat) {
  const int layer = blockIdx.z;
  const int K = (layer == 0) ? 1024 : 2048;
  const int N = (layer == 2) ? 1024 : 2048;
  if ((int)blockIdx.x >= (N >> 7) || (int)blockIdx.y >= (N >> 7)) return;
  const uint16_t* R = Wt + (layer == 0 ? 0 : (layer == 1 ? 2097152 : 6291456));
  float* C = Bmat + (layer == 0 ? 0 : (layer == 1 ? 4194304 : 8388608));

  __shared__ uint16_t lds[16384];  // 32KB: A-tile [128][64] | B-tile [128][64]
  const int t = threadIdx.x;
  const int w = t >> 6, lane = t & 63;
  const int m0 = blockIdx.y * 128, n0 = blockIdx.x * 128;
  const int wm = (w >> 1) * 64, wn = (w & 1) * 64;
  const size_t Kb = (size_t)K * 2;

  f32x4 zero = {0.f, 0.f, 0.f, 0.f};
  f32x4 acc[4][4];
#pragma unroll
  for (int i = 0; i < 4; ++i)
#pragma unroll
    for (int j = 0; j < 4; ++j) acc[i][j] = zero;

  const int rb = ((w < 2) ? m0 : n0) + (w & 1) * 64;
  const char* gsrc = (const char*)R + (size_t)rb * Kb;
  uint16_t* ltile = lds + (w < 2 ? 0 : 8192) + (w & 1) * 4096;
  const int lrow = lane >> 3;
  const int lcol = (lane & 7) * 16;

  int offA[4][2], offB[4][2];
#pragma unroll
  for (int i = 0; i < 4; ++i) {
    int rowa = wm + i * 16 + (lane & 15);
    int rowb = wn + i * 16 + (lane & 15);
    int kp = (lane >> 4) << 4;
#pragma unroll
    for (int kk = 0; kk < 2; ++kk) {
      offA[i][kk] = (rowa << 7) + (((kk << 6) + kp) ^ ((rowa & 7) << 4));
      offB[i][kk] = (rowb << 7) + (((kk << 6) + kp) ^ ((rowb & 7) << 4));
    }
  }
  const char* ldsc = (const char*)lds;
  const int nkt = K >> 6;
  for (int kt = 0; kt < nkt; ++kt) {
    const char* gb = gsrc + (size_t)kt * 128;
#pragma unroll
    for (int r = 0; r < 8; ++r) {
      gload16(gb + (size_t)(r * 8 + lrow) * Kb + lcol, ltile + r * 512);
    }
    __syncthreads();
#pragma unroll
    for (int kk = 0; kk < 2; ++kk) {
      bf16x8 af[4], bfr[4];
#pragma unroll
      for (int i = 0; i < 4; ++i) {
        af[i]  = *(const bf16x8*)(ldsc + offA[i][kk]);
        bfr[i] = *(const bf16x8*)(ldsc + 16384 + offB[i][kk]);
      }
#pragma unroll
      for (int i = 0; i < 4; ++i)
#pragma unroll
        for (int j = 0; j < 4; ++j)
          acc[i][j] = __builtin_amdgcn_mfma_f32_16x16x32_bf16(af[i], bfr[j], acc[i][j], 0, 0, 0);
    }
    __syncthreads();
  }
#pragma unroll
  for (int j = 0; j < 4; ++j) {
    int n = n0 + wn + j * 16 + (lane & 15);
#pragma unroll
    for (int i = 0; i < 4; ++i) {
      int mb = m0 + wm + i * 16 + ((lane >> 4) << 2);
      f32x4 a = acc[i][j];
#pragma unroll
      for (int r = 0; r < 4; ++r) C[(size_t)(mb + r) * N + n] = a[r];
    }
  }
}

// ---------------------------------------------------------------------------
// v1: v = W^T u0 per layer — wave per row of Wt (bf16 swizzled), fp32 accum
// ---------------------------------------------------------------------------
__global__ __launch_bounds__(256) void v1_kernel(const uint16_t* __restrict__ Wt,
                                                 const float* u00, const float* u01,
                                                 const float* u02,
                                                 float* __restrict__ vout) {
  int gw = (blockIdx.x * 256 + threadIdx.x) >> 6;  // 0..5119
  int lane = threadIdx.x & 63;
  int layer = gw < 2048 ? 0 : (gw < 4096 ? 1 : 2);
  int j = gw - (layer == 0 ? 0 : (layer == 1 ? 2048 : 4096));
  int ni = layer == 0 ? 1024 : 2048;
  const uint16_t* row = Wt + (layer == 0 ? 0 : (layer == 1 ? 2097152 : 6291456)) + (size_t)j * ni;
  const float* u0 = layer == 0 ? u00 : (layer == 1 ? u01 : u02);
  int nc = ni >> 3;
  float part = 0.f;
  for (int c = lane; c < nc; c += 64) {
    int bo = (c * 16) ^ ((j & 7) << 4);
    short8 v = *(const short8*)((const char*)row + bo);
    const float4* up = (const float4*)(u0 + c * 8);
    float4 a = up[0], b = up[1];
    float us[8] = {a.x, a.y, a.z, a.w, b.x, b.y, b.z, b.w};
#pragma unroll
    for (int e = 0; e < 8; ++e) part += bf2f((uint16_t)((short*)&v)[e]) * us[e];
  }
  for (int o = 32; o; o >>= 1) part += __shfl_xor(part, o, 64);
  if (lane == 0) vout[layer * 2048 + j] = part;
}

// ---------------------------------------------------------------------------
// bmv: vout = B vin for all 3 layers (wave per row, fp32)
// ---------------------------------------------------------------------------
__global__ __launch_bounds__(256) void bmv_kernel(const float* __restrict__ Bm,
                                                  const float* __restrict__ vin,
                                                  float* __restrict__ vout) {
  int gw = (blockIdx.x * 256 + threadIdx.x) >> 6;  // 0..5119
  int lane = threadIdx.x & 63;
  int layer = gw < 2048 ? 0 : (gw < 4096 ? 1 : 2);
  int r = gw - (layer == 0 ? 0 : (layer == 1 ? 2048 : 4096));
  int n = layer == 2 ? 1024 : 2048;
  const float* row = Bm + (layer == 0 ? 0 : (layer == 1 ? 4194304 : 8388608)) + (size_t)r * n;
  const float* v = vin + layer * 2048;
  float part = 0.f;
  for (int c = lane * 4; c < n; c += 256) {
    float4 w4 = *(const float4*)(row + c);
    float4 v4 = *(const float4*)(v + c);
    part += w4.x * v4.x + w4.y * v4.y + w4.z * v4.z + w4.w * v4.w;
  }
  for (int o = 32; o; o >>= 1) part += __shfl_xor(part, o, 64);
  if (lane == 0) vout[layer * 2048 + r] = part;
}

// ---------------------------------------------------------------------------
// dual GEMM: BK=32, DOUBLE-buffered 64KB (2 stages x 4 mats x [128][32]),
// T3 2-phase loop: stage(kt+1 -> buf^1) || ds_read(buf) + MFMA, one barrier
// per K-tile (its implicit vmcnt(0) drain lands AFTER compute).
// R5's proven-correct, conflict-free swizzle algebra (absmax 1.0, conflicts 0):
//   stage src byte = (kt*64 + ((lane&3)^((lane>>3)&3))<<4) ^ (((lane>>2)&7)<<4)
//   ds_read granule = ((lane>>4) ^ ((lane>>1)&3)) << 4
// launch_bounds(256,2): 128 acc AGPR + 64 frag VGPR + addr fits 2 blocks/CU
// (R5's (256,3) forced a scratch spill: FETCH 2GB, WRITE 2.8GB, 5.6x slowdown)
// ---------------------------------------------------------------------------
__global__ __launch_bounds__(256, 2) void gemm_dual_kernel(
    const uint16_t* __restrict__ Ab, const uint16_t* __restrict__ A2b,
    const uint16_t* __restrict__ Bb, const uint16_t* __restrict__ B2b,
    const float* __restrict__ eps, const float* __restrict__ bias,
    uint16_t* __restrict__ Oh, uint16_t* __restrict__ Oh2,
    float* __restrict__ Oy, int K, int N, int last, int nwgx) {
  __shared__ uint16_t lds[32768];  // 64KB: 2 x (A | A2 | B | B2), each [128][32]
  const int t = threadIdx.x;
  const int w = t >> 6, lane = t & 63;

  // T1: bijective XCD swizzle (grid always % 8 == 0 here)
  const int nwg = gridDim.x;
  const int cpx = nwg >> 3;
  const int bid = blockIdx.x;
  const int logical = (bid & 7) * cpx + (bid >> 3);
  const int bx = logical % nwgx, by = logical / nwgx;

  const int m0 = by * 128, n0 = bx * 128;
  const int wm = (w >> 1) * 64, wn = (w & 1) * 64;
  const size_t Kb = (size_t)K * 2;

  f32x4 zero = {0.f, 0.f, 0.f, 0.f};
  f32x4 accm[4][4], accs[4][4];
#pragma unroll
  for (int i = 0; i < 4; ++i)
#pragma unroll
    for (int j = 0; j < 4; ++j) { accm[i][j] = zero; accs[i][j] = zero; }

  // staging: wave w stages matrix w (A, A2, B, B2), 8KB per K-tile
  const uint16_t* mats[4] = {Ab, A2b, Bb, B2b};
  const int rbase = (w < 2) ? m0 : n0;
  const char* gsrc = (const char*)mats[w] + (size_t)rbase * Kb;
  const int rowq = lane >> 2;  // row within 16-row chunk
  const int soff = ((((lane & 3) ^ ((lane >> 3) & 3)) << 4));
  const int gmask = (((lane >> 2) & 7) << 4);

  // ds_read: physical granule = q ^ h(row'), h(row') = (lane>>1)&3
  const int kx = (((lane >> 4) ^ ((lane >> 1) & 3)) << 4);
  int offA[4], offB[4];
#pragma unroll
  for (int i = 0; i < 4; ++i) {
    offA[i] = ((wm + i * 16 + (lane & 15)) << 6) + kx;
    offB[i] = ((wn + i * 16 + (lane & 15)) << 6) + kx;
  }

  const int nkt = K >> 5;
  // prologue: stage K-tile 0 into buffer 0
  {
    char* lw = (char*)lds + w * 8192;
    int srcb = (0 * 64 + soff) ^ gmask;
#pragma unroll
    for (int rr = 0; rr < 8; ++rr)
      gload16(gsrc + (size_t)(rr * 16 + rowq) * Kb + srcb, lw + rr * 1024 + lane * 16);
  }
  __syncthreads();  // buffer 0 staged

  int cur = 0;
  for (int kt = 0; kt < nkt; ++kt) {
    // issue next-tile stage into the other buffer (flies under ds_read+MFMA)
    if (kt + 1 < nkt) {
      char* lw = (char*)lds + (cur ^ 1) * 32768 + w * 8192;
      int srcb = ((kt + 1) * 64 + soff) ^ gmask;
#pragma unroll
      for (int rr = 0; rr < 8; ++rr)
        gload16(gsrc + (size_t)(rr * 16 + rowq) * Kb + srcb, lw + rr * 1024 + lane * 16);
    }
    const char* sb = (const char*)lds + cur * 32768;
    bf16x8 af[4], a2f[4], bfr[4], b2f[4];
#pragma unroll
    for (int i = 0; i < 4; ++i) {
      af[i]  = *(const bf16x8*)(sb + offA[i]);
      a2f[i] = *(const bf16x8*)(sb + 8192 + offA[i]);
      bfr[i] = *(const bf16x8*)(sb + 16384 + offB[i]);
      b2f[i] = *(const bf16x8*)(sb + 24576 + offB[i]);
    }
#pragma unroll
    for (int i = 0; i < 4; ++i)
#pragma unroll
      for (int j = 0; j < 4; ++j) {
        accm[i][j] = __builtin_amdgcn_mfma_f32_16x16x32_bf16(af[i], bfr[j], accm[i][j], 0, 0, 0);
        accs[i][j] = __builtin_amdgcn_mfma_f32_16x16x32_bf16(a2f[i], b2f[j], accs[i][j], 0, 0, 0);
      }
    __syncthreads();  // drains stage(kt+1) vmcnt AFTER compute; one barrier/tile
    cur ^= 1;
  }

  // epilogue
  const int nstrb = N * 2;
#pragma unroll
  for (int j = 0; j < 4; ++j) {
    int n = n0 + wn + j * 16 + (lane & 15);
    float bn = bias[n];
#pragma unroll
    for (int i = 0; i < 4; ++i) {
      int mb = m0 + wm + i * 16 + ((lane >> 4) << 2);
      f32x4 am = accm[i][j], as = accs[i][j];
#pragma unroll
      for (int r = 0; r < 4; ++r) {
        int m = mb + r;
        float sd = sqrtf(fmaxf(as[r], 0.f));
        float val = am[r] + sd * eps[(size_t)m * N + n] + bn;
        if (last) {
          Oy[(size_t)m * N + n] = val;
        } else {
          float h = fmaxf(val, 0.f);
          size_t ob = (size_t)m * nstrb + ((n * 2) ^ ((m & 7) << 4));
          *(uint16_t*)((char*)Oh + ob) = f2bf(h);
          *(uint16_t*)((char*)Oh2 + ob) = f2bf(h * h);
        }
      }
    }
  }
}

// ---------------------------------------------------------------------------
// finalize: reduce sim partials; tkld, tlip.
// sigma = sqrt(dot(v10,Bv10)/dot(v10,v10))
// ---------------------------------------------------------------------------
__device__ __forceinline__ float block_red(float v, int is_max, float* red) {
  int t = threadIdx.x;
  red[t] = v;
  __syncthreads();
  for (int o = 128; o >= 1; o >>= 1) {
    if (t < o) red[t] = is_max ? fmaxf(red[t], red[t + o]) : (red[t] + red[t + o]);
    __syncthreads();
  }
  float r = red[0];
  __syncthreads();
  return r;
}

__global__ __launch_bounds__(256) void finalize_kernel(const float* __restrict__ acc,
                                                       const float* __restrict__ v10,
                                                       const float* __restrict__ wv,
                                                       const float* __restrict__ partial,
                                                       float* __restrict__ out2) {
  __shared__ float red[256];
  __shared__ float smax[30];
  int t = threadIdx.x;
  int w = t >> 6, lane = t & 63;
  for (int sl = w; sl < 30; sl += 4) {
    float m = 0.f;
    for (int b = lane; b < 2048; b += 64) m = fmaxf(m, partial[sl * 2048 + b]);
    for (int o = 32; o; o >>= 1) m = fmaxf(m, __shfl_xor(m, o, 64));
    if (lane == 0) smax[sl] = m;
  }
  __syncthreads();
  float tlip = 0.f;
  for (int layer = 0; layer < 3; ++layer) {
    int ni = layer == 0 ? 1024 : 2048;
    int no = layer == 2 ? 1024 : 2048;
    float mr = 0.f, mc = 0.f, s2n = 0.f, s2d = 0.f;
    for (int i = t; i < ni; i += 256) mr = fmaxf(mr, acc[64 + layer * 2048 + i]);
    for (int j = t; j < no; j += 256) mc = fmaxf(mc, acc[6208 + layer * 2048 + j]);
    for (int j = t; j < no; j += 256) {
      float v = v10[layer * 2048 + j], wv_ = wv[layer * 2048 + j];
      s2n += v * wv_;
      s2d += v * v;
    }
    mr = block_red(mr, 1, red);
    mc = block_red(mc, 1, red);
    s2n = block_red(s2n, 0, red);
    s2d = block_red(s2d, 0, red);
    if (t == 0) {
      float sm = 0.f;
      for (int s = 0; s < 10; ++s) sm += smax[layer * 10 + s];
      sm *= 0.1f;
      float sigma = sqrtf(s2n / s2d);
      float res = sqrtf(mr) + sqrtf(mc);
      float l = res + sm + sigma;
      tlip += l * l;
    }
  }
  if (t == 0) {
    out2[0] = acc[0];
    out2[1] = tlip;
  }
}

// ---------------------------------------------------------------------------
extern "C" void kernel_launch(void* const* d_in, const int* in_sizes, int n_in,
                              void* d_out, int out_size, void* d_ws, size_t ws_size,
                              hipStream_t stream) {
  (void)in_sizes; (void)n_in; (void)out_size; (void)ws_size;
  const float* x = (const float*)d_in[0];
  const float* Wmu[3] = {(const float*)d_in[1], (const float*)d_in[9],  (const float*)d_in[17]};
  const float* Wp[3]  = {(const float*)d_in[2], (const float*)d_in[10], (const float*)d_in[18]};
  const float* bmu[3] = {(const float*)d_in[3], (const float*)d_in[11], (const float*)d_in[19]};
  const float* bp[3]  = {(const float*)d_in[4], (const float*)d_in[12], (const float*)d_in[20]};
  const float* epsw[3]= {(const float*)d_in[5], (const float*)d_in[13], (const float*)d_in[21]};
  const float* epsb[3]= {(const float*)d_in[6], (const float*)d_in[14], (const float*)d_in[22]};
  const float* u0[3]  = {(const float*)d_in[7], (const float*)d_in[15], (const float*)d_in[23]};
  const float* sim[3] = {(const float*)d_in[8], (const float*)d_in[16], (const float*)d_in[24]};

  char* ws = (char*)d_ws;
  uint16_t* A0h  = (uint16_t*)(ws);
  uint16_t* A0h2 = (uint16_t*)(ws + 33554432);
  uint16_t* A1h  = (uint16_t*)(ws + 67108864);
  uint16_t* A1h2 = (uint16_t*)(ws + 100663296);
  float*    Bmat = (float*)(ws + 67108864);     // aliases A1h: dead before gemm1
  uint16_t* Sgbf = (uint16_t*)(ws + 104857600); // aliases A1h2 tail: dead before gemm1
  uint16_t* Wt   = (uint16_t*)(ws + 134217728);
  uint16_t* St2  = (uint16_t*)(ws + 150994944);
  float* bias    = (float*)(ws + 167772160);
  float* pbuf0   = (float*)(ws + 167796736);
  float* pbuf1   = (float*)(ws + 167821312);
  float* acc     = (float*)(ws + 167845888);
  float* partial = (float*)(ws + 167895296);    // 30*2048 floats
  // acc layout: [0] kld | [64..6207] row2 | [6208..12351] col2

  hipMemsetAsync(ws + 167845888, 0, 49408, stream);

  prep_w_kernel<<<dim3(32, 32, 3), 256, 0, stream>>>(
      Wmu[0], Wp[0], Wmu[1], Wp[1], Wmu[2], Wp[2], Wt, St2, Sgbf, acc + 64, acc + 6208, acc);
  prep_x_kernel<<<4096, 256, 0, stream>>>(x, A0h, A0h2);
  prep_bias_kernel<<<20, 256, 0, stream>>>(
      bmu[0], bp[0], epsb[0], bmu[1], bp[1], epsb[1], bmu[2], bp[2], epsb[2], bias, acc);
  sim_max_kernel<<<2048, 256, 0, stream>>>(sim[0], sim[1], sim[2], Sgbf, partial);

  // B = W^T W per layer (bf16 MFMA from Wt rows), one launch
  gemm_nt_kernel<<<dim3(16, 16, 3), 256, 0, stream>>>(Wt, Bmat);

  // v1 = W^T u0 ; then v_{k+1} = B v_k ; v10 in pbuf1, w = B v10 in pbuf0
  v1_kernel<<<1280, 256, 0, stream>>>(Wt, u0[0], u0[1], u0[2], pbuf0);
  for (int it = 0; it < 10; ++it) {
    const float* vin = (it & 1) ? pbuf1 : pbuf0;
    float* vout = (it & 1) ? pbuf0 : pbuf1;
    bmv_kernel<<<1280, 256, 0, stream>>>(Bmat, vin, vout);
  }

  float* y = (float*)d_out;
  gemm_dual_kernel<<<1024, 256, 0, stream>>>(
      A0h, A0h2, Wt, St2, epsw[0], bias, A1h, A1h2, nullptr, 1024, 2048, 0, 16);
  gemm_dual_kernel<<<1024, 256, 0, stream>>>(
      A1h, A1h2, Wt + 2097152, St2 + 2097152, epsw[1], bias + 2048, A0h, A0h2, nullptr, 2048, 2048, 0, 16);
  gemm_dual_kernel<<<512, 256, 0, stream>>>(
      A0h, A0h2, Wt + 6291456, St2 + 6291456, epsw[2], bias + 4096, nullptr, nullptr, y, 2048, 1024, 1, 8);

  finalize_kernel<<<1, 256, 0, stream>>>(acc, pbuf1, pbuf0, partial, y + 8388608);
}

// Round 7
// 883.430 us; speedup vs baseline: 3.7667x; 1.0374x over previous
//
#include <hip/hip_runtime.h>
#include <stdint.h>

typedef __attribute__((ext_vector_type(8))) __bf16 bf16x8;
typedef __attribute__((ext_vector_type(8))) short short8;
typedef __attribute__((ext_vector_type(4))) float f32x4;

#define LOG_P01 (-2.302585093f)   // log(0.1)

__device__ __forceinline__ uint16_t f2bf(float f) {
  union { float f; uint32_t u; } v; v.f = f;
  uint32_t r = (v.u + 0x7fffu + ((v.u >> 16) & 1u)) >> 16;
  return (uint16_t)r;
}
__device__ __forceinline__ float bf2f(uint16_t u) {
  union { uint32_t u; float f; } v; v.u = ((uint32_t)u) << 16;
  return v.f;
}
__device__ __forceinline__ float softplus1(float x) { return 1e-6f + log1pf(expf(x)); }

__device__ __forceinline__ void gload16(const void* g, void* l) {
  __builtin_amdgcn_global_load_lds(
      (__attribute__((address_space(1))) void*)(g),
      (__attribute__((address_space(3))) void*)(l), 16, 0, 0);
}

// ---------------------------------------------------------------------------
// prep_w: per 64x64 tile of W: sigma = 1e-6+softplus(W_p);
//   - write transposed, XOR-swizzled bf16 W_mu and sigma^2 (GEMM B operands)
//   - write plain-layout bf16 sigma (for sim_max)
//   - atomicAdd row/col norm^2 partials, KLD partial
// ---------------------------------------------------------------------------
__global__ __launch_bounds__(256) void prep_w_kernel(
    const float* __restrict__ Wmu0, const float* __restrict__ Wp0,
    const float* __restrict__ Wmu1, const float* __restrict__ Wp1,
    const float* __restrict__ Wmu2, const float* __restrict__ Wp2,
    uint16_t* __restrict__ Wt, uint16_t* __restrict__ St2,
    uint16_t* __restrict__ Sg,
    float* __restrict__ row2, float* __restrict__ col2, float* __restrict__ kld) {
  const int layer = blockIdx.z;
  const int ni = (layer == 0) ? 1024 : 2048;
  const int no = (layer == 2) ? 1024 : 2048;
  if ((int)blockIdx.x >= (ni >> 6) || (int)blockIdx.y >= (no >> 6)) return;
  const float* Wmu = layer == 0 ? Wmu0 : (layer == 1 ? Wmu1 : Wmu2);
  const float* Wp  = layer == 0 ? Wp0  : (layer == 1 ? Wp1  : Wp2);
  const size_t wofs = layer == 0 ? 0 : (layer == 1 ? 2097152 : 6291456);
  uint16_t* wt = Wt + wofs;
  uint16_t* st = St2 + wofs;
  uint16_t* sgb = Sg + wofs;
  float* r2 = row2 + layer * 2048;
  float* c2 = col2 + layer * 2048;

  __shared__ uint16_t lmu[64][72];
  __shared__ uint16_t ls2[64][72];
  __shared__ float red[256];

  const int t = threadIdx.x;
  const int i0 = blockIdx.x * 64, j0 = blockIdx.y * 64;
  const int w = t >> 6, lane = t & 63;
  float colpart = 0.f, kpart = 0.f;
#pragma unroll
  for (int rep = 0; rep < 16; ++rep) {
    int il = rep * 4 + w;
    int jl = lane;
    size_t gi = (size_t)(i0 + il) * no + (j0 + jl);
    float mu = Wmu[gi], p = Wp[gi];
    float sg = softplus1(p);
    float s2 = sg * sg;
    kpart += 2.f * (LOG_P01 - logf(sg)) - 1.f + 100.f * s2 + 100.f * mu * mu;
    float rs = s2;
    for (int o = 32; o; o >>= 1) rs += __shfl_xor(rs, o, 64);
    if (lane == 0) atomicAdd(&r2[i0 + il], rs);
    colpart += s2;
    sgb[gi] = f2bf(sg);
    lmu[jl][il] = f2bf(mu);
    ls2[jl][il] = f2bf(s2);
  }
  red[t] = colpart;
  __syncthreads();
  if (t < 64) {
    float cs = red[t] + red[64 + t] + red[128 + t] + red[192 + t];
    atomicAdd(&c2[j0 + t], cs);
  }
  // transposed, swizzled write-out (16B chunks): row j, byte (k*2)^((j&7)<<4)
  const int Kb = ni * 2;
#pragma unroll
  for (int cc = 0; cc < 2; ++cc) {
    int c = cc * 256 + t;
    int nl = c >> 3, kc = c & 7;
    short8 vmu = *(const short8*)((const char*)&lmu[0][0] + nl * 144 + kc * 16);
    short8 vs2 = *(const short8*)((const char*)&ls2[0][0] + nl * 144 + kc * 16);
    size_t db = (size_t)(j0 + nl) * Kb + (((i0 * 2 + kc * 16)) ^ ((nl & 7) << 4));
    *(short8*)((char*)wt + db) = vmu;
    *(short8*)((char*)st + db) = vs2;
  }
  __syncthreads();
  red[t] = kpart;
  __syncthreads();
  for (int o = 128; o >= 1; o >>= 1) {
    if (t < o) red[t] += red[t + o];
    __syncthreads();
  }
  if (t == 0) atomicAdd(kld, 0.5f * red[0]);
}

// ---------------------------------------------------------------------------
// prep_x: bf16(x), bf16(x*x) into swizzled [8192][1024] layout
// ---------------------------------------------------------------------------
__global__ __launch_bounds__(256) void prep_x_kernel(const float* __restrict__ x,
                                                     uint16_t* __restrict__ Ah,
                                                     uint16_t* __restrict__ Ah2) {
  size_t c = (size_t)blockIdx.x * 256 + threadIdx.x;  // 8-elem chunk
  size_t gidx = c * 8;
  if (gidx >= (size_t)8192 * 1024) return;
  int m = (int)(gidx >> 10);
  int k0 = (int)(gidx & 1023);
  const float4* xp = (const float4*)(x + gidx);
  float4 a = xp[0], b = xp[1];
  float vals[8] = {a.x, a.y, a.z, a.w, b.x, b.y, b.z, b.w};
  union { uint16_t u[8]; short8 v; } ph, ph2;
#pragma unroll
  for (int e = 0; e < 8; ++e) {
    float f = vals[e];
    ph.u[e] = f2bf(f);
    ph2.u[e] = f2bf(f * f);
  }
  size_t ob = (size_t)m * 2048 + ((k0 * 2) ^ ((m & 7) << 4));
  *(short8*)((char*)Ah + ob) = ph.v;
  *(short8*)((char*)Ah2 + ob) = ph2.v;
}

// ---------------------------------------------------------------------------
// prep_bias: bias[n] = b_mu + softplus(b_p)*eps_b ; bias KLD
// ---------------------------------------------------------------------------
__global__ __launch_bounds__(256) void prep_bias_kernel(
    const float* bmu0, const float* bp0, const float* eb0,
    const float* bmu1, const float* bp1, const float* eb1,
    const float* bmu2, const float* bp2, const float* eb2,
    float* __restrict__ bias, float* __restrict__ kld) {
  int t = blockIdx.x * 256 + threadIdx.x;
  float kpart = 0.f;
  if (t < 5120) {
    int layer = t < 2048 ? 0 : (t < 4096 ? 1 : 2);
    int n = t - (layer == 0 ? 0 : (layer == 1 ? 2048 : 4096));
    const float* bmu = layer == 0 ? bmu0 : (layer == 1 ? bmu1 : bmu2);
    const float* bp  = layer == 0 ? bp0  : (layer == 1 ? bp1  : bp2);
    const float* eb  = layer == 0 ? eb0  : (layer == 1 ? eb1  : eb2);
    float mu = bmu[n], p = bp[n], e = eb[n];
    float sg = softplus1(p);
    bias[layer * 2048 + n] = mu + sg * e;
    kpart = 0.5f * (2.f * (LOG_P01 - logf(sg)) - 1.f + 100.f * sg * sg + 100.f * mu * mu);
  }
  for (int o = 32; o; o >>= 1) kpart += __shfl_xor(kpart, o, 64);
  if ((threadIdx.x & 63) == 0) atomicAdd(kld, kpart);
}

// ---------------------------------------------------------------------------
// sim_max: single linear grid-stride pass over concatenated sim (320MB).
// ---------------------------------------------------------------------------
__global__ __launch_bounds__(256) void sim_max_kernel(
    const float* __restrict__ s0, const float* __restrict__ s1,
    const float* __restrict__ s2, const uint16_t* __restrict__ Sg,
    float* __restrict__ partial) {
  __shared__ int lmax[30];
  if (threadIdx.x < 30) lmax[threadIdx.x] = 0;
  __syncthreads();
  const size_t stride = (size_t)gridDim.x * 256;
  for (size_t c = (size_t)blockIdx.x * 256 + threadIdx.x; c < 20971520; c += stride) {
    const float* sp; size_t within; const uint16_t* sgp; int slot_base, shift;
    if (c < 5242880)       { sp = s0; within = c;            sgp = Sg;           slot_base = 0;  shift = 19; }
    else if (c < 15728640) { sp = s1; within = c - 5242880;  sgp = Sg + 2097152; slot_base = 10; shift = 20; }
    else                   { sp = s2; within = c - 15728640; sgp = Sg + 6291456; slot_base = 20; shift = 19; }
    int s = (int)(within >> shift);
    size_t idx = within - ((size_t)s << shift);
    float4 v = ((const float4*)sp)[within];
    ushort4 sv = *(const ushort4*)(sgp + idx * 4);
    float m = fmaxf(fmaxf(v.x * bf2f(sv.x), v.y * bf2f(sv.y)),
                    fmaxf(v.z * bf2f(sv.z), v.w * bf2f(sv.w)));
    for (int o = 32; o; o >>= 1) m = fmaxf(m, __shfl_xor(m, o, 64));
    if ((threadIdx.x & 63) == 0)
      atomicMax(&lmax[slot_base + s], __float_as_int(fmaxf(m, 0.f)));
  }
  __syncthreads();
  if (threadIdx.x < 30)
    partial[threadIdx.x * 2048 + blockIdx.x] = __int_as_float(lmax[threadIdx.x]);
}

// ---------------------------------------------------------------------------
// gemm_nt (3 layers in one launch): C = R @ R^T, R = Wt rows (bf16 swizzled).
// ---------------------------------------------------------------------------
__global__ __launch_bounds__(256, 2) void gemm_nt_kernel(
    const uint16_t* __restrict__ Wt, float* __restrict__ Bmat) {
  const int layer = blockIdx.z;
  const int K = (layer == 0) ? 1024 : 2048;
  const int N = (layer == 2) ? 1024 : 2048;
  if ((int)blockIdx.x >= (N >> 7) || (int)blockIdx.y >= (N >> 7)) return;
  const uint16_t* R = Wt + (layer == 0 ? 0 : (layer == 1 ? 2097152 : 6291456));
  float* C = Bmat + (layer == 0 ? 0 : (layer == 1 ? 4194304 : 8388608));

  __shared__ uint16_t lds[16384];  // 32KB: A-tile [128][64] | B-tile [128][64]
  const int t = threadIdx.x;
  const int w = t >> 6, lane = t & 63;
  const int m0 = blockIdx.y * 128, n0 = blockIdx.x * 128;
  const int wm = (w >> 1) * 64, wn = (w & 1) * 64;
  const size_t Kb = (size_t)K * 2;

  f32x4 zero = {0.f, 0.f, 0.f, 0.f};
  f32x4 acc[4][4];
#pragma unroll
  for (int i = 0; i < 4; ++i)
#pragma unroll
    for (int j = 0; j < 4; ++j) acc[i][j] = zero;

  const int rb = ((w < 2) ? m0 : n0) + (w & 1) * 64;
  const char* gsrc = (const char*)R + (size_t)rb * Kb;
  uint16_t* ltile = lds + (w < 2 ? 0 : 8192) + (w & 1) * 4096;
  const int lrow = lane >> 3;
  const int lcol = (lane & 7) * 16;

  int offA[4][2], offB[4][2];
#pragma unroll
  for (int i = 0; i < 4; ++i) {
    int rowa = wm + i * 16 + (lane & 15);
    int rowb = wn + i * 16 + (lane & 15);
    int kp = (lane >> 4) << 4;
#pragma unroll
    for (int kk = 0; kk < 2; ++kk) {
      offA[i][kk] = (rowa << 7) + (((kk << 6) + kp) ^ ((rowa & 7) << 4));
      offB[i][kk] = (rowb << 7) + (((kk << 6) + kp) ^ ((rowb & 7) << 4));
    }
  }
  const char* ldsc = (const char*)lds;
  const int nkt = K >> 6;
  for (int kt = 0; kt < nkt; ++kt) {
    const char* gb = gsrc + (size_t)kt * 128;
#pragma unroll
    for (int r = 0; r < 8; ++r) {
      gload16(gb + (size_t)(r * 8 + lrow) * Kb + lcol, ltile + r * 512);
    }
    __syncthreads();
#pragma unroll
    for (int kk = 0; kk < 2; ++kk) {
      bf16x8 af[4], bfr[4];
#pragma unroll
      for (int i = 0; i < 4; ++i) {
        af[i]  = *(const bf16x8*)(ldsc + offA[i][kk]);
        bfr[i] = *(const bf16x8*)(ldsc + 16384 + offB[i][kk]);
      }
#pragma unroll
      for (int i = 0; i < 4; ++i)
#pragma unroll
        for (int j = 0; j < 4; ++j)
          acc[i][j] = __builtin_amdgcn_mfma_f32_16x16x32_bf16(af[i], bfr[j], acc[i][j], 0, 0, 0);
    }
    __syncthreads();
  }
#pragma unroll
  for (int j = 0; j < 4; ++j) {
    int n = n0 + wn + j * 16 + (lane & 15);
#pragma unroll
    for (int i = 0; i < 4; ++i) {
      int mb = m0 + wm + i * 16 + ((lane >> 4) << 2);
      f32x4 a = acc[i][j];
#pragma unroll
      for (int r = 0; r < 4; ++r) C[(size_t)(mb + r) * N + n] = a[r];
    }
  }
}

// ---------------------------------------------------------------------------
// v1: v = W^T u0 per layer — wave per row of Wt (bf16 swizzled), fp32 accum
// ---------------------------------------------------------------------------
__global__ __launch_bounds__(256) void v1_kernel(const uint16_t* __restrict__ Wt,
                                                 const float* u00, const float* u01,
                                                 const float* u02,
                                                 float* __restrict__ vout) {
  int gw = (blockIdx.x * 256 + threadIdx.x) >> 6;  // 0..5119
  int lane = threadIdx.x & 63;
  int layer = gw < 2048 ? 0 : (gw < 4096 ? 1 : 2);
  int j = gw - (layer == 0 ? 0 : (layer == 1 ? 2048 : 4096));
  int ni = layer == 0 ? 1024 : 2048;
  const uint16_t* row = Wt + (layer == 0 ? 0 : (layer == 1 ? 2097152 : 6291456)) + (size_t)j * ni;
  const float* u0 = layer == 0 ? u00 : (layer == 1 ? u01 : u02);
  int nc = ni >> 3;
  float part = 0.f;
  for (int c = lane; c < nc; c += 64) {
    int bo = (c * 16) ^ ((j & 7) << 4);
    short8 v = *(const short8*)((const char*)row + bo);
    const float4* up = (const float4*)(u0 + c * 8);
    float4 a = up[0], b = up[1];
    float us[8] = {a.x, a.y, a.z, a.w, b.x, b.y, b.z, b.w};
#pragma unroll
    for (int e = 0; e < 8; ++e) part += bf2f((uint16_t)((short*)&v)[e]) * us[e];
  }
  for (int o = 32; o; o >>= 1) part += __shfl_xor(part, o, 64);
  if (lane == 0) vout[layer * 2048 + j] = part;
}

// ---------------------------------------------------------------------------
// bmv: vout = B vin for all 3 layers (wave per row, fp32)
// ---------------------------------------------------------------------------
__global__ __launch_bounds__(256) void bmv_kernel(const float* __restrict__ Bm,
                                                  const float* __restrict__ vin,
                                                  float* __restrict__ vout) {
  int gw = (blockIdx.x * 256 + threadIdx.x) >> 6;  // 0..5119
  int lane = threadIdx.x & 63;
  int layer = gw < 2048 ? 0 : (gw < 4096 ? 1 : 2);
  int r = gw - (layer == 0 ? 0 : (layer == 1 ? 2048 : 4096));
  int n = layer == 2 ? 1024 : 2048;
  const float* row = Bm + (layer == 0 ? 0 : (layer == 1 ? 4194304 : 8388608)) + (size_t)r * n;
  const float* v = vin + layer * 2048;
  float part = 0.f;
  for (int c = lane * 4; c < n; c += 256) {
    float4 w4 = *(const float4*)(row + c);
    float4 v4 = *(const float4*)(v + c);
    part += w4.x * v4.x + w4.y * v4.y + w4.z * v4.z + w4.w * v4.w;
  }
  for (int o = 32; o; o >>= 1) part += __shfl_xor(part, o, 64);
  if (lane == 0) vout[layer * 2048 + r] = part;
}

// ---------------------------------------------------------------------------
// dual GEMM, ROLE-SPLIT: 512 threads / 8 waves per block, 128x128 tile.
// Waves 0-3: mu = A@B for quadrant (w>>1, w&1); waves 4-7: s = A2@B2, same
// quadrant. Per-wave acc = 64 regs (was 128) -> launch_bounds(512,4) targets
// <=128 VGPR so 2 blocks/CU = 16 waves/CU (2x R6's occupancy).
// BK=64, single 64KB buffer, R3's proven 2-barrier schedule + swizzle algebra.
// Epilogue: s-waves exchange sd=sqrt(max(acc,0)) via 64KB LDS (index-
// symmetric layout, 2 lanes/bank = conflict-free), mu-waves fuse+write.
// ---------------------------------------------------------------------------
__global__ __launch_bounds__(512, 4) void gemm_dual_kernel(
    const uint16_t* __restrict__ Ab, const uint16_t* __restrict__ A2b,
    const uint16_t* __restrict__ Bb, const uint16_t* __restrict__ B2b,
    const float* __restrict__ eps, const float* __restrict__ bias,
    uint16_t* __restrict__ Oh, uint16_t* __restrict__ Oh2,
    float* __restrict__ Oy, int K, int N, int last, int nwgx) {
  __shared__ uint16_t lds[32768];  // 64KB: A | A2 | B | B2, each [128][64]
  const int t = threadIdx.x;
  const int w = t >> 6, lane = t & 63;

  // T1: bijective XCD swizzle (grid always % 8 == 0 here)
  const int nwg = gridDim.x;
  const int cpx = nwg >> 3;
  const int bid = blockIdx.x;
  const int logical = (bid & 7) * cpx + (bid >> 3);
  const int bx = logical % nwgx, by = logical / nwgx;

  const int m0 = by * 128, n0 = bx * 128;
  const int wq = w & 3;                    // quadrant id (shared mu/s)
  const int is_s = w >> 2;                 // 0 = mu role, 1 = s role
  const int wm = (wq >> 1) * 64, wn = (wq & 1) * 64;
  const size_t Kb = (size_t)K * 2;

  f32x4 zero = {0.f, 0.f, 0.f, 0.f};
  f32x4 acc[4][4];
#pragma unroll
  for (int i = 0; i < 4; ++i)
#pragma unroll
    for (int j = 0; j < 4; ++j) acc[i][j] = zero;

  // staging: wave w stages mat (w>>1), row-half (w&1): 64 rows x 128B = 8KB
  const uint16_t* mats[4] = {Ab, A2b, Bb, B2b};
  const int mymat = w >> 1;
  const int rbase = ((mymat < 2) ? m0 : n0) + (w & 1) * 64;
  const char* gsrc = (const char*)mats[mymat] + (size_t)rbase * Kb;
  char* lw = (char*)lds + mymat * 16384 + (w & 1) * 8192;
  const int lrow = lane >> 3;
  const int lcol = (lane & 7) * 16;

  // ds_read offsets (R3-proven): base by role
  const int abase = is_s ? 16384 : 0;      // A or A2 tile
  const int bbase = is_s ? 49152 : 32768;  // B or B2 tile
  const int kp = (lane >> 4) << 4;
  int offA[4][2], offB[4][2];
#pragma unroll
  for (int i = 0; i < 4; ++i) {
    int rowa = wm + i * 16 + (lane & 15);
    int rowb = wn + i * 16 + (lane & 15);
#pragma unroll
    for (int kk = 0; kk < 2; ++kk) {
      offA[i][kk] = abase + (rowa << 7) + (((kk << 6) + kp) ^ ((rowa & 7) << 4));
      offB[i][kk] = bbase + (rowb << 7) + (((kk << 6) + kp) ^ ((rowb & 7) << 4));
    }
  }
  const char* ldsc = (const char*)lds;
  const int nkt = K >> 6;
  for (int kt = 0; kt < nkt; ++kt) {
    const char* gb = gsrc + (size_t)kt * 128;
#pragma unroll
    for (int rr = 0; rr < 8; ++rr)
      gload16(gb + (size_t)(rr * 8 + lrow) * Kb + lcol, lw + rr * 1024 + lane * 16);
    __syncthreads();
#pragma unroll
    for (int kk = 0; kk < 2; ++kk) {
      bf16x8 af[4], bfr[4];
#pragma unroll
      for (int i = 0; i < 4; ++i) {
        af[i]  = *(const bf16x8*)(ldsc + offA[i][kk]);
        bfr[i] = *(const bf16x8*)(ldsc + offB[i][kk]);
      }
#pragma unroll
      for (int i = 0; i < 4; ++i)
#pragma unroll
        for (int j = 0; j < 4; ++j)
          acc[i][j] = __builtin_amdgcn_mfma_f32_16x16x32_bf16(af[i], bfr[j], acc[i][j], 0, 0, 0);
    }
    __syncthreads();
  }

  // ---- sd exchange: s-wave wq <-> mu-wave wq, same lane, same frag index ----
  float* xch = (float*)lds;
  if (is_s) {
#pragma unroll
    for (int i = 0; i < 4; ++i)
#pragma unroll
      for (int j = 0; j < 4; ++j)
#pragma unroll
        for (int r = 0; r < 4; ++r)
          xch[(i * 16 + j * 4 + r) * 256 + wq * 64 + lane] = sqrtf(fmaxf(acc[i][j][r], 0.f));
  }
  __syncthreads();
  if (!is_s) {
    const int nstrb = N * 2;
#pragma unroll
    for (int j = 0; j < 4; ++j) {
      int n = n0 + wn + j * 16 + (lane & 15);
      float bn = bias[n];
#pragma unroll
      for (int i = 0; i < 4; ++i) {
        int mb = m0 + wm + i * 16 + ((lane >> 4) << 2);
        f32x4 am = acc[i][j];
#pragma unroll
        for (int r = 0; r < 4; ++r) {
          int m = mb + r;
          float sd = xch[(i * 16 + j * 4 + r) * 256 + wq * 64 + lane];
          float val = am[r] + sd * eps[(size_t)m * N + n] + bn;
          if (last) {
            Oy[(size_t)m * N + n] = val;
          } else {
            float h = fmaxf(val, 0.f);
            size_t ob = (size_t)m * nstrb + ((n * 2) ^ ((m & 7) << 4));
            *(uint16_t*)((char*)Oh + ob) = f2bf(h);
            *(uint16_t*)((char*)Oh2 + ob) = f2bf(h * h);
          }
        }
      }
    }
  }
}

// ---------------------------------------------------------------------------
// finalize: reduce sim partials; tkld, tlip.
// sigma = sqrt(dot(v10,Bv10)/dot(v10,v10))
// ---------------------------------------------------------------------------
__device__ __forceinline__ float block_red(float v, int is_max, float* red) {
  int t = threadIdx.x;
  red[t] = v;
  __syncthreads();
  for (int o = 128; o >= 1; o >>= 1) {
    if (t < o) red[t] = is_max ? fmaxf(red[t], red[t + o]) : (red[t] + red[t + o]);
    __syncthreads();
  }
  float r = red[0];
  __syncthreads();
  return r;
}

__global__ __launch_bounds__(256) void finalize_kernel(const float* __restrict__ acc,
                                                       const float* __restrict__ v10,
                                                       const float* __restrict__ wv,
                                                       const float* __restrict__ partial,
                                                       float* __restrict__ out2) {
  __shared__ float red[256];
  __shared__ float smax[30];
  int t = threadIdx.x;
  int w = t >> 6, lane = t & 63;
  for (int sl = w; sl < 30; sl += 4) {
    float m = 0.f;
    for (int b = lane; b < 2048; b += 64) m = fmaxf(m, partial[sl * 2048 + b]);
    for (int o = 32; o; o >>= 1) m = fmaxf(m, __shfl_xor(m, o, 64));
    if (lane == 0) smax[sl] = m;
  }
  __syncthreads();
  float tlip = 0.f;
  for (int layer = 0; layer < 3; ++layer) {
    int ni = layer == 0 ? 1024 : 2048;
    int no = layer == 2 ? 1024 : 2048;
    float mr = 0.f, mc = 0.f, s2n = 0.f, s2d = 0.f;
    for (int i = t; i < ni; i += 256) mr = fmaxf(mr, acc[64 + layer * 2048 + i]);
    for (int j = t; j < no; j += 256) mc = fmaxf(mc, acc[6208 + layer * 2048 + j]);
    for (int j = t; j < no; j += 256) {
      float v = v10[layer * 2048 + j], wv_ = wv[layer * 2048 + j];
      s2n += v * wv_;
      s2d += v * v;
    }
    mr = block_red(mr, 1, red);
    mc = block_red(mc, 1, red);
    s2n = block_red(s2n, 0, red);
    s2d = block_red(s2d, 0, red);
    if (t == 0) {
      float sm = 0.f;
      for (int s = 0; s < 10; ++s) sm += smax[layer * 10 + s];
      sm *= 0.1f;
      float sigma = sqrtf(s2n / s2d);
      float res = sqrtf(mr) + sqrtf(mc);
      float l = res + sm + sigma;
      tlip += l * l;
    }
  }
  if (t == 0) {
    out2[0] = acc[0];
    out2[1] = tlip;
  }
}

// ---------------------------------------------------------------------------
extern "C" void kernel_launch(void* const* d_in, const int* in_sizes, int n_in,
                              void* d_out, int out_size, void* d_ws, size_t ws_size,
                              hipStream_t stream) {
  (void)in_sizes; (void)n_in; (void)out_size; (void)ws_size;
  const float* x = (const float*)d_in[0];
  const float* Wmu[3] = {(const float*)d_in[1], (const float*)d_in[9],  (const float*)d_in[17]};
  const float* Wp[3]  = {(const float*)d_in[2], (const float*)d_in[10], (const float*)d_in[18]};
  const float* bmu[3] = {(const float*)d_in[3], (const float*)d_in[11], (const float*)d_in[19]};
  const float* bp[3]  = {(const float*)d_in[4], (const float*)d_in[12], (const float*)d_in[20]};
  const float* epsw[3]= {(const float*)d_in[5], (const float*)d_in[13], (const float*)d_in[21]};
  const float* epsb[3]= {(const float*)d_in[6], (const float*)d_in[14], (const float*)d_in[22]};
  const float* u0[3]  = {(const float*)d_in[7], (const float*)d_in[15], (const float*)d_in[23]};
  const float* sim[3] = {(const float*)d_in[8], (const float*)d_in[16], (const float*)d_in[24]};

  char* ws = (char*)d_ws;
  uint16_t* A0h  = (uint16_t*)(ws);
  uint16_t* A0h2 = (uint16_t*)(ws + 33554432);
  uint16_t* A1h  = (uint16_t*)(ws + 67108864);
  uint16_t* A1h2 = (uint16_t*)(ws + 100663296);
  float*    Bmat = (float*)(ws + 67108864);     // aliases A1h: dead before gemm1
  uint16_t* Sgbf = (uint16_t*)(ws + 104857600); // aliases A1h2 tail: dead before gemm1
  uint16_t* Wt   = (uint16_t*)(ws + 134217728);
  uint16_t* St2  = (uint16_t*)(ws + 150994944);
  float* bias    = (float*)(ws + 167772160);
  float* pbuf0   = (float*)(ws + 167796736);
  float* pbuf1   = (float*)(ws + 167821312);
  float* acc     = (float*)(ws + 167845888);
  float* partial = (float*)(ws + 167895296);    // 30*2048 floats
  // acc layout: [0] kld | [64..6207] row2 | [6208..12351] col2

  hipMemsetAsync(ws + 167845888, 0, 49408, stream);

  prep_w_kernel<<<dim3(32, 32, 3), 256, 0, stream>>>(
      Wmu[0], Wp[0], Wmu[1], Wp[1], Wmu[2], Wp[2], Wt, St2, Sgbf, acc + 64, acc + 6208, acc);
  prep_x_kernel<<<4096, 256, 0, stream>>>(x, A0h, A0h2);
  prep_bias_kernel<<<20, 256, 0, stream>>>(
      bmu[0], bp[0], epsb[0], bmu[1], bp[1], epsb[1], bmu[2], bp[2], epsb[2], bias, acc);
  sim_max_kernel<<<2048, 256, 0, stream>>>(sim[0], sim[1], sim[2], Sgbf, partial);

  // B = W^T W per layer (bf16 MFMA from Wt rows), one launch
  gemm_nt_kernel<<<dim3(16, 16, 3), 256, 0, stream>>>(Wt, Bmat);

  // v1 = W^T u0 ; then v_{k+1} = B v_k ; v10 in pbuf1, w = B v10 in pbuf0
  v1_kernel<<<1280, 256, 0, stream>>>(Wt, u0[0], u0[1], u0[2], pbuf0);
  for (int it = 0; it < 10; ++it) {
    const float* vin = (it & 1) ? pbuf1 : pbuf0;
    float* vout = (it & 1) ? pbuf0 : pbuf1;
    bmv_kernel<<<1280, 256, 0, stream>>>(Bmat, vin, vout);
  }

  float* y = (float*)d_out;
  gemm_dual_kernel<<<1024, 512, 0, stream>>>(
      A0h, A0h2, Wt, St2, epsw[0], bias, A1h, A1h2, nullptr, 1024, 2048, 0, 16);
  gemm_dual_kernel<<<1024, 512, 0, stream>>>(
      A1h, A1h2, Wt + 2097152, St2 + 2097152, epsw[1], bias + 2048, A0h, A0h2, nullptr, 2048, 2048, 0, 16);
  gemm_dual_kernel<<<512, 512, 0, stream>>>(
      A0h, A0h2, Wt + 6291456, St2 + 6291456, epsw[2], bias + 4096, nullptr, nullptr, y, 2048, 1024, 1, 8);

  finalize_kernel<<<1, 256, 0, stream>>>(acc, pbuf1, pbuf0, partial, y + 8388608);
}